// Round 1
// baseline (648.378 us; speedup 1.0000x reference)
//
#include <hip/hip_runtime.h>
#include <hip/hip_bf16.h>
#include <stdint.h>

#define NR 16384
#define DIM 512
#define BM 128
#define BN 128
#define BK 32
#define NKT (DIM / BK)

typedef __bf16 bf16x8 __attribute__((ext_vector_type(8)));
typedef float f32x4 __attribute__((ext_vector_type(4)));

__device__ inline ushort f2bf(float x) {
  uint32_t u = __float_as_uint(x);
  uint32_t r = (u + 0x7FFFu + ((u >> 16) & 1u)) >> 16;
  return (ushort)r;
}

// Kernel 1: fp32 -> bf16 conversion for both matrices + fused diagonal dot.
// One wave per row; lane handles float4 idx {lane, lane+64} (coalesced).
__global__ __launch_bounds__(256) void convert_diag(
    const float* __restrict__ I, const float* __restrict__ T,
    const float* __restrict__ scale_p,
    ushort* __restrict__ bI, ushort* __restrict__ bT,
    float* __restrict__ diag)
{
  int wid = threadIdx.x >> 6;
  int lane = threadIdx.x & 63;
  int row = blockIdx.x * 4 + wid;
  const float4* I4 = (const float4*)(I + (size_t)row * DIM);
  const float4* T4 = (const float4*)(T + (size_t)row * DIM);
  ushort* bIr = bI + (size_t)row * DIM;
  ushort* bTr = bT + (size_t)row * DIM;
  float dot = 0.f;
#pragma unroll
  for (int h = 0; h < 2; ++h) {
    int idx = lane + h * 64;
    float4 a = I4[idx];
    float4 b = T4[idx];
    dot += a.x * b.x + a.y * b.y + a.z * b.z + a.w * b.w;
    ushort4 ha, hb;
    ha.x = f2bf(a.x); ha.y = f2bf(a.y); ha.z = f2bf(a.z); ha.w = f2bf(a.w);
    hb.x = f2bf(b.x); hb.y = f2bf(b.y); hb.z = f2bf(b.z); hb.w = f2bf(b.w);
    *(ushort4*)(bIr + (size_t)idx * 4) = ha;
    *(ushort4*)(bTr + (size_t)idx * 4) = hb;
  }
#pragma unroll
  for (int off = 32; off > 0; off >>= 1) dot += __shfl_down(dot, off);
  if (lane == 0) diag[row] = scale_p[0] * dot;
}

// Kernel 2: 128x128-tile bf16 MFMA GEMM (C = I * T^T, both row-major [N][D])
// fused with per-tile row/col online-softmax partials (max, sumexp).
__global__ __launch_bounds__(256) void gemm_lse(
    const ushort* __restrict__ bI, const ushort* __restrict__ bT,
    const float* __restrict__ scale_p,
    float2* __restrict__ rowPart, float2* __restrict__ colPart)
{
  __shared__ __align__(16) ushort As[2][BM * BK];
  __shared__ __align__(16) ushort Bs[2][BN * BK];
  __shared__ float2 redRow[BM][2];
  __shared__ float2 redCol[BN][2];

  // XCD-aware bijective swizzle: nwg = 16384, divisible by 8.
  int bid = blockIdx.x;
  int swz = (bid & 7) * (16384 / 8) + (bid >> 3);
  int bi = swz >> 7;       // tile row   (0..127)
  int bj = swz & 127;      // tile col   (0..127)

  int tid = threadIdx.x;
  int w = tid >> 6, lane = tid & 63;
  int wr = w >> 1, wc = w & 1;   // 2x2 wave grid, 64x64 per wave

  f32x4 acc[4][4];
#pragma unroll
  for (int m = 0; m < 4; ++m)
#pragma unroll
    for (int n = 0; n < 4; ++n)
      acc[m][n] = (f32x4){0.f, 0.f, 0.f, 0.f};

  int r4 = lane >> 2;            // row within 16-row chunk
  int c8 = (lane & 3) * 8;       // bf16 col offset within BK

  auto stage = [&](int buf, int kt) {
#pragma unroll
    for (int L = 0; L < 2; ++L) {
      int c = L * 4 + w;         // chunk 0..7, 16 rows each
      const ushort* gA = bI + ((size_t)(bi * BM + c * 16 + r4) * DIM + kt * BK + c8);
      __builtin_amdgcn_global_load_lds(
          (const __attribute__((address_space(1))) void*)gA,
          (__attribute__((address_space(3))) void*)&As[buf][c * 16 * BK], 16, 0, 0);
      const ushort* gB = bT + ((size_t)(bj * BN + c * 16 + r4) * DIM + kt * BK + c8);
      __builtin_amdgcn_global_load_lds(
          (const __attribute__((address_space(1))) void*)gB,
          (__attribute__((address_space(3))) void*)&Bs[buf][c * 16 * BK], 16, 0, 0);
    }
  };

  stage(0, 0);
  __syncthreads();

  int buf = 0;
  for (int kt = 0; kt < NKT; ++kt) {
    if (kt + 1 < NKT) stage(buf ^ 1, kt + 1);
    int aBase = (wr * 64 + (lane & 15)) * BK + (lane >> 4) * 8;
    int bBase = (wc * 64 + (lane & 15)) * BK + (lane >> 4) * 8;
    bf16x8 aF[4], bF[4];
#pragma unroll
    for (int m = 0; m < 4; ++m) aF[m] = *(const bf16x8*)&As[buf][aBase + m * 16 * BK];
#pragma unroll
    for (int n = 0; n < 4; ++n) bF[n] = *(const bf16x8*)&Bs[buf][bBase + n * 16 * BK];
#pragma unroll
    for (int m = 0; m < 4; ++m)
#pragma unroll
      for (int n = 0; n < 4; ++n)
        acc[m][n] = __builtin_amdgcn_mfma_f32_16x16x32_bf16(aF[m], bF[n], acc[m][n], 0, 0, 0);
    __syncthreads();
    buf ^= 1;
  }

  // ---- epilogue: scale, then per-tile row/col (max, sumexp) partials ----
  float sc = scale_p[0];
#pragma unroll
  for (int m = 0; m < 4; ++m)
#pragma unroll
    for (int n = 0; n < 4; ++n)
      acc[m][n] = acc[m][n] * sc;

  // C/D layout (m89-verified): col = lane&15, row = (lane>>4)*4 + reg.
  // Row partials: reduce over cols = over n-frags (in-lane) x (lane&15).
#pragma unroll
  for (int m = 0; m < 4; ++m) {
#pragma unroll
    for (int j = 0; j < 4; ++j) {
      float rm = fmaxf(fmaxf(acc[m][0][j], acc[m][1][j]),
                       fmaxf(acc[m][2][j], acc[m][3][j]));
#pragma unroll
      for (int msk = 1; msk <= 8; msk <<= 1) rm = fmaxf(rm, __shfl_xor(rm, msk));
      float rs = 0.f;
#pragma unroll
      for (int n = 0; n < 4; ++n) rs += __expf(acc[m][n][j] - rm);
#pragma unroll
      for (int msk = 1; msk <= 8; msk <<= 1) rs += __shfl_xor(rs, msk);
      if ((lane & 15) == 0) {
        int r = wr * 64 + m * 16 + (lane >> 4) * 4 + j;
        redRow[r][wc] = make_float2(rm, rs);
      }
    }
  }
  // Col partials: reduce over rows = over m-frags, regs (in-lane) x (lane>>4).
#pragma unroll
  for (int n = 0; n < 4; ++n) {
    float cm = -1e30f;
#pragma unroll
    for (int m = 0; m < 4; ++m)
#pragma unroll
      for (int j = 0; j < 4; ++j) cm = fmaxf(cm, acc[m][n][j]);
    cm = fmaxf(cm, __shfl_xor(cm, 16));
    cm = fmaxf(cm, __shfl_xor(cm, 32));
    float csum = 0.f;
#pragma unroll
    for (int m = 0; m < 4; ++m)
#pragma unroll
      for (int j = 0; j < 4; ++j) csum += __expf(acc[m][n][j] - cm);
    csum += __shfl_xor(csum, 16);
    csum += __shfl_xor(csum, 32);
    if (lane < 16) {
      int cidx = wc * 64 + n * 16 + lane;
      redCol[cidx][wr] = make_float2(cm, csum);
    }
  }
  __syncthreads();

  // Combine the two waves sharing rows (wc=0/1) / cols (wr=0/1); write partials.
  if (tid < BM) {
    float2 p0 = redRow[tid][0], p1 = redRow[tid][1];
    float m_ = fmaxf(p0.x, p1.x);
    float s_ = p0.y * __expf(p0.x - m_) + p1.y * __expf(p1.x - m_);
    rowPart[(size_t)bj * NR + bi * BM + tid] = make_float2(m_, s_);
  } else {
    int t = tid - BM;
    float2 p0 = redCol[t][0], p1 = redCol[t][1];
    float m_ = fmaxf(p0.x, p1.x);
    float s_ = p0.y * __expf(p0.x - m_) + p1.y * __expf(p1.x - m_);
    colPart[(size_t)bi * NR + bj * BN + t] = make_float2(m_, s_);
  }
}

// Kernel 3: merge 128 partials per row/col, subtract diag, accumulate mean.
__global__ __launch_bounds__(256) void reduce_final(
    const float2* __restrict__ rowPart, const float2* __restrict__ colPart,
    const float* __restrict__ diag, float* __restrict__ out)
{
  int bid = blockIdx.x;            // 0..127 ; first 64 rows, last 64 cols
  bool isCol = bid >= 64;
  int i = (bid & 63) * 256 + threadIdx.x;
  const float2* part = isCol ? colPart : rowPart;
  float m = -1e30f, s = 0.f;
  for (int b = 0; b < 128; ++b) {
    float2 p = part[(size_t)b * NR + i];
    float mn = fmaxf(m, p.x);
    s = s * __expf(m - mn) + p.y * __expf(p.x - mn);
    m = mn;
  }
  float contrib = (m + __logf(s)) - diag[i];
#pragma unroll
  for (int off = 32; off > 0; off >>= 1) contrib += __shfl_down(contrib, off);
  __shared__ float wsum[4];
  int wid = threadIdx.x >> 6, lane = threadIdx.x & 63;
  if (lane == 0) wsum[wid] = contrib;
  __syncthreads();
  if (threadIdx.x == 0) {
    float tot = wsum[0] + wsum[1] + wsum[2] + wsum[3];
    atomicAdd(out, tot * (1.0f / (2.0f * NR)));
  }
}

extern "C" void kernel_launch(void* const* d_in, const int* in_sizes, int n_in,
                              void* d_out, int out_size, void* d_ws, size_t ws_size,
                              hipStream_t stream) {
  const float* I = (const float*)d_in[0];
  const float* T = (const float*)d_in[1];
  const float* scale = (const float*)d_in[2];
  float* out = (float*)d_out;

  char* ws = (char*)d_ws;
  ushort* bI      = (ushort*)(ws);                          // 16 MB
  ushort* bT      = (ushort*)(ws + ((size_t)16 << 20));     // 16 MB
  float2* rowPart = (float2*)(ws + ((size_t)32 << 20));     // 16 MB
  float2* colPart = (float2*)(ws + ((size_t)48 << 20));     // 16 MB
  float*  diag    = (float*) (ws + ((size_t)64 << 20));     // 64 KB

  hipMemsetAsync(d_out, 0, sizeof(float), stream);
  convert_diag<<<NR / 4, 256, 0, stream>>>(I, T, scale, bI, bT, diag);
  gemm_lse<<<16384, 256, 0, stream>>>(bI, bT, scale, rowPart, colPart);
  reduce_final<<<128, 256, 0, stream>>>(rowPart, colPart, diag, out);
}

// Round 4
// 514.502 us; speedup vs baseline: 1.2602x; 1.2602x over previous
//
#include <hip/hip_runtime.h>
#include <hip/hip_bf16.h>
#include <stdint.h>

#define NR 16384
#define DIM 512
#define BK 32
#define NT (DIM / BK)      // 16 K-tiles
#define NTILE (NR / 256)   // 64 tile rows/cols
#define TILE_US (256 * BK) // 8192 ushorts = 16 KB per matrix per buffer

typedef __bf16 bf16x8 __attribute__((ext_vector_type(8)));
typedef float f32x4 __attribute__((ext_vector_type(4)));

__device__ inline ushort f2bf(float x) {
  uint32_t u = __float_as_uint(x);
  uint32_t r = (u + 0x7FFFu + ((u >> 16) & 1u)) >> 16;
  return (ushort)r;
}

// Kernel 1: fp32 -> bf16 (RNE) for both matrices + fused diagonal dot.
__global__ __launch_bounds__(256) void convert_diag(
    const float* __restrict__ I, const float* __restrict__ T,
    const float* __restrict__ scale_p,
    ushort* __restrict__ bI, ushort* __restrict__ bT,
    float* __restrict__ diag)
{
  int wid = threadIdx.x >> 6;
  int lane = threadIdx.x & 63;
  int row = blockIdx.x * 4 + wid;
  const float4* I4 = (const float4*)(I + (size_t)row * DIM);
  const float4* T4 = (const float4*)(T + (size_t)row * DIM);
  ushort* bIr = bI + (size_t)row * DIM;
  ushort* bTr = bT + (size_t)row * DIM;
  float dot = 0.f;
#pragma unroll
  for (int h = 0; h < 2; ++h) {
    int idx = lane + h * 64;
    float4 a = I4[idx];
    float4 b = T4[idx];
    dot += a.x * b.x + a.y * b.y + a.z * b.z + a.w * b.w;
    ushort4 ha, hb;
    ha.x = f2bf(a.x); ha.y = f2bf(a.y); ha.z = f2bf(a.z); ha.w = f2bf(a.w);
    hb.x = f2bf(b.x); hb.y = f2bf(b.y); hb.z = f2bf(b.z); hb.w = f2bf(b.w);
    *(ushort4*)(bIr + (size_t)idx * 4) = ha;
    *(ushort4*)(bTr + (size_t)idx * 4) = hb;
  }
#pragma unroll
  for (int off = 32; off > 0; off >>= 1) dot += __shfl_down(dot, off);
  if (lane == 0) diag[row] = scale_p[0] * dot;
}

// Kernel 2: 256x256-tile bf16 MFMA GEMM, 8 waves (2x4), BK=32,
// triple-buffered LDS + counted vmcnt(4) (never 0 in main loop),
// XOR bank-swizzle (both-sides), fused row/col LSE partials.
__global__ __launch_bounds__(512, 2) void gemm_lse(
    const ushort* __restrict__ bI, const ushort* __restrict__ bT,
    const float* __restrict__ scale_p,
    float2* __restrict__ rowPart, float2* __restrict__ colPart)
{
  __shared__ __align__(16) ushort As[3][TILE_US];
  __shared__ __align__(16) ushort Bs[3][TILE_US];

  // XCD-aware: XCD x owns an 8(bi) x 64(bj) slab; bi FAST so ~32 concurrent
  // blocks share 4 B-panels + an A-slab (~3 MB < 4 MB L2).
  int bid = blockIdx.x;
  int x = bid & 7, s = bid >> 3;        // nwg=4096, %8==0 -> bijective
  int bi = x * 8 + (s & 7);             // 0..63
  int bj = s >> 3;                      // 0..63

  int tid = threadIdx.x;
  int w = tid >> 6, lane = tid & 63;
  int wr = w >> 2, wc = w & 3;          // 2x4 wave grid; wave tile 128x64

  const ushort* gA = bI + (size_t)bi * 256 * DIM;
  const ushort* gB = bT + (size_t)bj * 256 * DIM;

  // staging: 1 global_load_lds per thread per half-tile (128 rows x 32 cols).
  // LDS written linearly (lane*16B): row = tid>>2, phys slot = tid&3.
  // Pre-swizzle SOURCE so logical slot (tid&3)^g(row) lands there, g(r)=(r>>1)&3.
  int srow = tid >> 2;
  int sslot = (tid & 3) ^ ((tid >> 3) & 3);

  auto stage = [&](ushort* dstTile, const ushort* srcMat, int kt, int h) {
    const ushort* g = srcMat + (size_t)(h * 128 + srow) * DIM + kt * BK + sslot * 8;
    ushort* d = dstTile + (h * 128 + w * 16) * BK;  // wave-uniform base
    __builtin_amdgcn_global_load_lds(
        (const __attribute__((address_space(1))) void*)g,
        (__attribute__((address_space(3))) void*)d, 16, 0, 0);
  };

  f32x4 acc[8][4];
#pragma unroll
  for (int m = 0; m < 8; ++m)
#pragma unroll
    for (int n = 0; n < 4; ++n)
      acc[m][n] = (f32x4){0.f, 0.f, 0.f, 0.f};

  // prologue: stage K-tiles 0 and 1; wait for K-tile 0 only (4 stay in flight)
  stage(As[0], gA, 0, 0); stage(As[0], gA, 0, 1);
  stage(Bs[0], gB, 0, 0); stage(Bs[0], gB, 0, 1);
  stage(As[1], gA, 1, 0); stage(As[1], gA, 1, 1);
  stage(Bs[1], gB, 1, 0); stage(Bs[1], gB, 1, 1);
  asm volatile("s_waitcnt vmcnt(4)" ::: "memory");
  __builtin_amdgcn_sched_barrier(0);
  __builtin_amdgcn_s_barrier();

  int aRow0 = wr * 128 + (lane & 15);
  int bRow0 = wc * 64 + (lane & 15);
  int sLog = lane >> 4;                 // logical 16B slot within row

  auto ldFrag = [&](const ushort* tile, int row) -> bf16x8 {
    int off = row * (BK * 2) + ((sLog ^ ((row >> 1) & 3)) << 4);
    return *(const bf16x8*)((const char*)tile + off);
  };

  int buf = 0, nb = 2;
  for (int t = 0; t < NT; ++t) {
    const ushort* At = As[buf];
    const ushort* Bt = Bs[buf];
    ushort* An = As[nb];
    ushort* Bn = Bs[nb];
    bool pf = (t + 2 < NT);

    // ---- phase 0: m0-3 x n0-3, prefetch next-next A halves ----
    bf16x8 aF[4], bF[4], aG[4];
#pragma unroll
    for (int m = 0; m < 4; ++m) aF[m] = ldFrag(At, aRow0 + m * 16);
#pragma unroll
    for (int n = 0; n < 4; ++n) bF[n] = ldFrag(Bt, bRow0 + n * 16);
    if (pf) { stage(An, gA, t + 2, 0); stage(An, gA, t + 2, 1); }
    __builtin_amdgcn_sched_barrier(0);
    __builtin_amdgcn_s_setprio(1);
#pragma unroll
    for (int m = 0; m < 4; ++m)
#pragma unroll
      for (int n = 0; n < 4; ++n)
        acc[m][n] = __builtin_amdgcn_mfma_f32_16x16x32_bf16(aF[m], bF[n], acc[m][n], 0, 0, 0);
    __builtin_amdgcn_s_setprio(0);
    __builtin_amdgcn_sched_barrier(0);

    // ---- phase 1: m4-7 x n0-3, prefetch next-next B halves ----
#pragma unroll
    for (int m = 0; m < 4; ++m) aG[m] = ldFrag(At, aRow0 + 64 + m * 16);
    if (pf) { stage(Bn, gB, t + 2, 0); stage(Bn, gB, t + 2, 1); }
    __builtin_amdgcn_sched_barrier(0);
    __builtin_amdgcn_s_setprio(1);
#pragma unroll
    for (int m = 0; m < 4; ++m)
#pragma unroll
      for (int n = 0; n < 4; ++n)
        acc[m + 4][n] = __builtin_amdgcn_mfma_f32_16x16x32_bf16(aG[m], bF[n], acc[m + 4][n], 0, 0, 0);
    __builtin_amdgcn_s_setprio(0);

    // ---- K-tile boundary: counted wait (t+1 landed; t+2 stays in flight) ----
    if (pf) asm volatile("s_waitcnt vmcnt(4)" ::: "memory");
    else    asm volatile("s_waitcnt vmcnt(0)" ::: "memory");
    __builtin_amdgcn_sched_barrier(0);
    __builtin_amdgcn_s_barrier();

    buf = (buf == 2) ? 0 : buf + 1;
    nb  = (nb == 2) ? 0 : nb + 1;
  }

  // ---- epilogue: scale + per-tile row/col (max, sumexp) partials ----
  float sc = scale_p[0];
#pragma unroll
  for (int m = 0; m < 8; ++m)
#pragma unroll
    for (int n = 0; n < 4; ++n)
      acc[m][n] *= sc;

  float2* redRow = (float2*)&As[0][0];  // [256][4]
  float2* redCol = (float2*)&Bs[0][0];  // [256][2]

  // C/D layout: col = lane&15, row = (lane>>4)*4 + reg.
#pragma unroll
  for (int m = 0; m < 8; ++m) {
#pragma unroll
    for (int j = 0; j < 4; ++j) {
      float rm = fmaxf(fmaxf(acc[m][0][j], acc[m][1][j]),
                       fmaxf(acc[m][2][j], acc[m][3][j]));
#pragma unroll
      for (int msk = 1; msk <= 8; msk <<= 1) rm = fmaxf(rm, __shfl_xor(rm, msk));
      float rs = 0.f;
#pragma unroll
      for (int n = 0; n < 4; ++n) rs += __expf(acc[m][n][j] - rm);
#pragma unroll
      for (int msk = 1; msk <= 8; msk <<= 1) rs += __shfl_xor(rs, msk);
      if ((lane & 15) == 0) {
        int r = wr * 128 + m * 16 + (lane >> 4) * 4 + j;
        redRow[r * 4 + wc] = make_float2(rm, rs);
      }
    }
  }
#pragma unroll
  for (int n = 0; n < 4; ++n) {
    float cm = -1e30f;
#pragma unroll
    for (int m = 0; m < 8; ++m)
#pragma unroll
      for (int j = 0; j < 4; ++j) cm = fmaxf(cm, acc[m][n][j]);
    cm = fmaxf(cm, __shfl_xor(cm, 16));
    cm = fmaxf(cm, __shfl_xor(cm, 32));
    float cs = 0.f;
#pragma unroll
    for (int m = 0; m < 8; ++m)
#pragma unroll
      for (int j = 0; j < 4; ++j) cs += __expf(acc[m][n][j] - cm);
    cs += __shfl_xor(cs, 16);
    cs += __shfl_xor(cs, 32);
    if (lane < 16) {
      int c = wc * 64 + n * 16 + lane;
      redCol[c * 2 + wr] = make_float2(cm, cs);
    }
  }
  __syncthreads();

  if (tid < 256) {
    float2 p = redRow[tid * 4];
    float m_ = p.x, s_ = p.y;
#pragma unroll
    for (int q = 1; q < 4; ++q) {
      float2 r = redRow[tid * 4 + q];
      float mn = fmaxf(m_, r.x);
      s_ = s_ * __expf(m_ - mn) + r.y * __expf(r.x - mn);
      m_ = mn;
    }
    rowPart[(size_t)bj * NR + bi * 256 + tid] = make_float2(m_, s_);
  } else {
    int c = tid - 256;
    float2 p0 = redCol[c * 2], p1 = redCol[c * 2 + 1];
    float mn = fmaxf(p0.x, p1.x);
    float s_ = p0.y * __expf(p0.x - mn) + p1.y * __expf(p1.x - mn);
    colPart[(size_t)bi * NR + bj * 256 + c] = make_float2(mn, s_);
  }
}

// Kernel 3: merge 64 partials per row/col, subtract diag, accumulate mean.
__global__ __launch_bounds__(256) void reduce_final(
    const float2* __restrict__ rowPart, const float2* __restrict__ colPart,
    const float* __restrict__ diag, float* __restrict__ out)
{
  int bid = blockIdx.x;            // 0..127; first 64 rows, last 64 cols
  bool isCol = bid >= 64;
  int i = (bid & 63) * 256 + threadIdx.x;
  const float2* part = isCol ? colPart : rowPart;
  float m = -1e30f, s = 0.f;
  for (int b = 0; b < NTILE; ++b) {
    float2 p = part[(size_t)b * NR + i];
    float mn = fmaxf(m, p.x);
    s = s * __expf(m - mn) + p.y * __expf(p.x - mn);
    m = mn;
  }
  float contrib = (m + __logf(s)) - diag[i];
#pragma unroll
  for (int off = 32; off > 0; off >>= 1) contrib += __shfl_down(contrib, off);
  __shared__ float wsum[4];
  int wid = threadIdx.x >> 6, lane = threadIdx.x & 63;
  if (lane == 0) wsum[wid] = contrib;
  __syncthreads();
  if (threadIdx.x == 0) {
    float tot = wsum[0] + wsum[1] + wsum[2] + wsum[3];
    atomicAdd(out, tot * (1.0f / (2.0f * NR)));
  }
}

extern "C" void kernel_launch(void* const* d_in, const int* in_sizes, int n_in,
                              void* d_out, int out_size, void* d_ws, size_t ws_size,
                              hipStream_t stream) {
  const float* I = (const float*)d_in[0];
  const float* T = (const float*)d_in[1];
  const float* scale = (const float*)d_in[2];
  float* out = (float*)d_out;

  char* ws = (char*)d_ws;
  ushort* bI      = (ushort*)(ws);                          // 16 MB
  ushort* bT      = (ushort*)(ws + ((size_t)16 << 20));     // 16 MB
  float2* rowPart = (float2*)(ws + ((size_t)32 << 20));     // 8 MB used
  float2* colPart = (float2*)(ws + ((size_t)48 << 20));     // 8 MB used
  float*  diag    = (float*) (ws + ((size_t)64 << 20));     // 64 KB

  hipMemsetAsync(d_out, 0, sizeof(float), stream);
  convert_diag<<<NR / 4, 256, 0, stream>>>(I, T, scale, bI, bT, diag);
  gemm_lse<<<NTILE * NTILE, 512, 0, stream>>>(bI, bT, scale, rowPart, colPart);
  reduce_final<<<128, 256, 0, stream>>>(rowPart, colPart, diag, out);
}